// Round 1
// 1747.980 us; speedup vs baseline: 1.6435x; 1.6435x over previous
//
#include <hip/hip_runtime.h>
#include <hip/hip_bf16.h>
#include <math.h>

// NTM forward, fully fused: one block per batch element, T=64 steps in-kernel.
// M[1024][64] fp32 lives in registers: 512 threads x 2 rows x 64 floats.
// This revision: weights are repacked TRANSPOSED into the workspace once per
// launch so every GEMV reads its reduction dim contiguously with dwordx4
// loads (8 bf16 / 4 fp32 per load) instead of 2-byte column-strided scalar
// loads. Identical FMA order -> identical numerics.

constexpr int kB  = 64;
constexpr int kT  = 64;
constexpr int kIN = 64;
constexpr int kC  = 256;
constexpr int kN  = 1024;
constexpr int kMV = 64;
constexpr int kOUT = 64;
constexpr int kHW = 198;   // write head raw dim: MV+6+2*MV
constexpr int kHR = 70;    // read head raw dim: MV+6
constexpr int NT  = 512;   // threads per block (8 waves)
constexpr float kEPS = 1e-8f;

// packed (transposed) weight layout, offsets in elements
constexpr int kPWc = 0;                          // WcT [256][128]
constexpr int kPWw = kPWc + kC * 128;            // WwT [198][256] @ 32768
constexpr int kPWr = kPWw + kHW * kC;            // WrT [70][256]  @ 83456
constexpr int kPWf = kPWr + kHR * kC;            // WfT [64][320]  @ 101376
constexpr int kPTotal = kPWf + kOUT * (kC + kMV);  // 121856 elements
constexpr size_t kWsNeeded = 256 + (size_t)kPTotal * 4;  // fp32 worst case

__device__ __forceinline__ float ldf(const float* p, int i) { return p[i]; }
__device__ __forceinline__ float ldf(const __hip_bfloat16* p, int i) { return __bfloat162float(p[i]); }
__device__ __forceinline__ void stf(float* p, int i, float v) { p[i] = v; }
__device__ __forceinline__ void stf(__hip_bfloat16* p, int i, float v) { p[i] = __float2bfloat16(v); }

// 8 contiguous elements -> float[8]; 16B-aligned by construction.
__device__ __forceinline__ void ld8(const __hip_bfloat16* p, float* f) {
  uint4 u = *reinterpret_cast<const uint4*>(p);
  f[0] = __uint_as_float(u.x << 16); f[1] = __uint_as_float(u.x & 0xffff0000u);
  f[2] = __uint_as_float(u.y << 16); f[3] = __uint_as_float(u.y & 0xffff0000u);
  f[4] = __uint_as_float(u.z << 16); f[5] = __uint_as_float(u.z & 0xffff0000u);
  f[6] = __uint_as_float(u.w << 16); f[7] = __uint_as_float(u.w & 0xffff0000u);
}
__device__ __forceinline__ void ld8(const float* p, float* f) {
  float4 a = reinterpret_cast<const float4*>(p)[0];
  float4 b = reinterpret_cast<const float4*>(p)[1];
  f[0] = a.x; f[1] = a.y; f[2] = a.z; f[3] = a.w;
  f[4] = b.x; f[5] = b.y; f[6] = b.z; f[7] = b.w;
}

__device__ __forceinline__ float sigmoidf_(float v) { return 1.f / (1.f + expf(-v)); }
__device__ __forceinline__ float softplusf_(float v) { return v > 20.f ? v : log1pf(expf(v)); }

__device__ __forceinline__ float wsum(float v) {
  v += __shfl_xor(v, 32); v += __shfl_xor(v, 16); v += __shfl_xor(v, 8);
  v += __shfl_xor(v, 4);  v += __shfl_xor(v, 2);  v += __shfl_xor(v, 1);
  return v;
}
__device__ __forceinline__ float wmax(float v) {
  v = fmaxf(v, __shfl_xor(v, 32)); v = fmaxf(v, __shfl_xor(v, 16));
  v = fmaxf(v, __shfl_xor(v, 8));  v = fmaxf(v, __shfl_xor(v, 4));
  v = fmaxf(v, __shfl_xor(v, 2));  v = fmaxf(v, __shfl_xor(v, 1));
  return v;
}

struct Smem {
  float in[kIN + kMV];      // controller input concat(x_t, r)
  float c[kC];              // controller activations
  float h[kHW];             // write head raw
  float hr[kHR];            // read head raw
  float k[kMV], kr[kMV], e[kMV], a[kMV], r[kMV];
  float part[8][kC];        // GEMM partials
  float wg[kN];             // interpolated weights (for circular shift)
  float red[3][8];          // cross-wave reduction slots
  float scal[16];           // 0..6 write head: beta,g,gamma,s0,s1,s2,|k| ; 8..14 read head
  float tmp[NT][17];        // read-vector column reduction (pad 17 -> conflict-free)
};

__device__ __forceinline__ void address2(Smem& sm, int tid, int lane, int wid,
                                         float sim0, float sim1,
                                         float g, float s0, float s1, float s2, float gamma,
                                         float wp0, float wp1,
                                         float& w0, float& w1) {
  float m = wmax(fmaxf(sim0, sim1));
  if (lane == 0) sm.red[0][wid] = m;
  __syncthreads();
  float gmax = sm.red[0][0];
  #pragma unroll
  for (int i = 1; i < NT / 64; ++i) gmax = fmaxf(gmax, sm.red[0][i]);
  float e0 = expf(sim0 - gmax), e1 = expf(sim1 - gmax);
  float sv = wsum(e0 + e1);
  if (lane == 0) sm.red[1][wid] = sv;
  __syncthreads();
  float gsum = 0.f;
  #pragma unroll
  for (int i = 0; i < NT / 64; ++i) gsum += sm.red[1][i];
  float inv = 1.f / gsum;
  float wg0 = fmaf(g, fmaf(e0, inv, -wp0), wp0);
  float wg1 = fmaf(g, fmaf(e1, inv, -wp1), wp1);
  sm.wg[tid] = wg0; sm.wg[tid + NT] = wg1;
  __syncthreads();
  // circular conv: s[0]*w[n+1] + s[1]*w[n] + s[2]*w[n-1]  (SHIFTS = -1,0,+1)
  float ws0 = s0 * sm.wg[(tid + 1) & (kN - 1)] + s1 * wg0 + s2 * sm.wg[(tid + kN - 1) & (kN - 1)];
  float ws1 = s0 * sm.wg[(tid + NT + 1) & (kN - 1)] + s1 * wg1 + s2 * sm.wg[(tid + NT - 1) & (kN - 1)];
  float p0 = expf(gamma * logf(ws0 + kEPS));
  float p1 = expf(gamma * logf(ws1 + kEPS));
  float pv = wsum(p0 + p1);
  if (lane == 0) sm.red[2][wid] = pv;
  __syncthreads();
  float psum = 0.f;
  #pragma unroll
  for (int i = 0; i < NT / 64; ++i) psum += sm.red[2][i];
  float ipn = 1.f / psum;
  w0 = p0 * ipn; w1 = p1 * ipn;
}

// flag: 1 if buffers are bf16, 0 if fp32.  w_bias is a softmax -> sums to 1.
// Parallel: 64 lanes, shuffle-reduced (old serial version cost ~50us).
__global__ void detect_dtype(const void* wb, int* flag) {
  const unsigned short* u = (const unsigned short*)wb;
  int lane = threadIdx.x;
  float s = 0.f;
  for (int i = lane; i < kN; i += 64)
    s += __uint_as_float(((unsigned int)u[i]) << 16);
  s = wsum(s);
  if (lane == 0 && blockIdx.x == 0)
    *flag = (s > 0.75f && s < 1.25f) ? 1 : 0;
}

// Transpose-repack the four weight matrices into workspace (coalesced writes).
template <typename TD, int WANT>
__global__ void repack_w(const TD* __restrict__ Wc, const TD* __restrict__ Ww,
                         const TD* __restrict__ Wr, const TD* __restrict__ Wf,
                         TD* __restrict__ pk, const int* __restrict__ flag) {
  if (*flag != WANT) return;
  for (int idx = blockIdx.x * blockDim.x + threadIdx.x; idx < kPTotal;
       idx += gridDim.x * blockDim.x) {
    TD v;
    if (idx < kPWw) {                       // WcT[j][i] = Wc[i][j], [128][256] src
      int r = idx, j = r >> 7, i = r & 127;
      v = Wc[i * kC + j];
    } else if (idx < kPWr) {                // WwT[j][i] = Ww[i][j], [256][198] src
      int r = idx - kPWw, j = r >> 8, i = r & 255;
      v = Ww[i * kHW + j];
    } else if (idx < kPWf) {                // WrT[j][i] = Wr[i][j], [256][70] src
      int r = idx - kPWr, j = r >> 8, i = r & 255;
      v = Wr[i * kHR + j];
    } else {                                // WfT[j][i] = Wf[i][j], [320][64] src
      int r = idx - kPWf, j = r / 320, i = r % 320;
      v = Wf[i * kOUT + j];
    }
    pk[idx] = v;
  }
}

template <typename TD, int WANT, int PACKED>
__global__ __launch_bounds__(NT, 2) void ntm_fused(
    const TD* __restrict__ x,
    const TD* __restrict__ Wc, const TD* __restrict__ bc,
    const TD* __restrict__ Wr, const TD* __restrict__ br,
    const TD* __restrict__ Ww, const TD* __restrict__ bw,
    const TD* __restrict__ Wf, const TD* __restrict__ bf,
    const TD* __restrict__ r_bias, const TD* __restrict__ w_bias,
    const TD* __restrict__ M_bias,
    const TD* __restrict__ pk,
    TD* __restrict__ out, const int* __restrict__ flag) {
  if (*flag != WANT) return;
  __shared__ Smem sm;
  const int tid  = threadIdx.x;
  const int b    = blockIdx.x;
  const int lane = tid & 63;
  const int wid  = tid >> 6;

  const TD* pWcT = pk + kPWc;
  const TD* pWwT = pk + kPWw;
  const TD* pWrT = pk + kPWr;
  const TD* pWfT = pk + kPWf;

  // ---- init state: M rows (registers), row norms, prev weights, read vector
  float M0[kMV], M1[kMV];
  float n2_0 = 0.f, n2_1 = 0.f;
  #pragma unroll
  for (int j = 0; j < kMV; ++j) {
    M0[j] = ldf(M_bias, tid * kMV + j);
    M1[j] = ldf(M_bias, (tid + NT) * kMV + j);
    n2_0 = fmaf(M0[j], M0[j], n2_0);
    n2_1 = fmaf(M1[j], M1[j], n2_1);
  }
  float wp0 = ldf(w_bias, tid);
  float wp1 = ldf(w_bias, tid + NT);
  if (tid < kMV) sm.r[tid] = ldf(r_bias, tid);
  __syncthreads();

  #pragma unroll 1
  for (int t = 0; t < kT; ++t) {
    // ---- stage controller input [x_t, r]
    if (tid < kIN) sm.in[tid] = ldf(x, (b * kT + t) * kIN + tid);
    else if (tid < kIN + kMV) sm.in[tid] = sm.r[tid - kIN];
    __syncthreads();

    // ---- controller: c = tanh(in @ Wc + bc)   (256 outs, 128 in; 2 partials)
    {
      const int j = tid & 255, p = tid >> 8;
      float s = 0.f;
      if constexpr (PACKED) {
        const TD* row = pWcT + j * 128 + p * 64;   // contiguous 64 elems
        #pragma unroll
        for (int q = 0; q < 8; ++q) {
          float f[8]; ld8(row + 8 * q, f);
          #pragma unroll
          for (int u = 0; u < 8; ++u)
            s = fmaf(sm.in[p * 64 + 8 * q + u], f[u], s);
        }
      } else {
        #pragma unroll 8
        for (int i = 0; i < 64; ++i)
          s = fmaf(sm.in[p * 64 + i], ldf(Wc, (p * 64 + i) * kC + j), s);
      }
      sm.part[p][j] = s;
    }
    __syncthreads();
    if (tid < kC) sm.c[tid] = tanhf(sm.part[0][tid] + sm.part[1][tid] + ldf(bc, tid));
    __syncthreads();

    // ---- head GEMMs: hw = c @ Ww + bw (198), hr = c @ Wr + br (70)
    {
      const int j = tid & 255, p = tid >> 8;
      if (j < kHW) {
        float s = 0.f;
        if constexpr (PACKED) {
          const TD* row = pWwT + j * kC + p * 128;  // contiguous 128 elems
          #pragma unroll
          for (int q = 0; q < 16; ++q) {
            float f[8]; ld8(row + 8 * q, f);
            #pragma unroll
            for (int u = 0; u < 8; ++u)
              s = fmaf(sm.c[p * 128 + 8 * q + u], f[u], s);
          }
        } else {
          #pragma unroll 8
          for (int i = 0; i < 128; ++i)
            s = fmaf(sm.c[p * 128 + i], ldf(Ww, (p * 128 + i) * kHW + j), s);
        }
        sm.part[p][j] = s;
      }
      if (j < kHR) {
        float s = 0.f;
        if constexpr (PACKED) {
          const TD* row = pWrT + j * kC + p * 128;
          #pragma unroll
          for (int q = 0; q < 16; ++q) {
            float f[8]; ld8(row + 8 * q, f);
            #pragma unroll
            for (int u = 0; u < 8; ++u)
              s = fmaf(sm.c[p * 128 + 8 * q + u], f[u], s);
          }
        } else {
          #pragma unroll 8
          for (int i = 0; i < 128; ++i)
            s = fmaf(sm.c[p * 128 + i], ldf(Wr, (p * 128 + i) * kHR + j), s);
        }
        sm.part[2 + p][j] = s;
      }
    }
    __syncthreads();
    if (tid < kHW) sm.h[tid] = sm.part[0][tid] + sm.part[1][tid] + ldf(bw, tid);
    if (tid >= 256 && tid < 256 + kHR) {
      int j = tid - 256;
      sm.hr[j] = sm.part[2][j] + sm.part[3][j] + ldf(br, j);
    }
    __syncthreads();

    // ---- head params (wave-uniform branches)
    if (wid == 0) {                       // write key + |k|
      float kv = tanhf(sm.h[lane]); sm.k[lane] = kv;
      float s = wsum(kv * kv);
      if (lane == 0) sm.scal[6] = sqrtf(s);
    } else if (wid == 1) {                // erase
      sm.e[lane] = sigmoidf_(sm.h[70 + lane]);
    } else if (wid == 2) {                // add
      sm.a[lane] = tanhf(sm.h[134 + lane]);
    } else if (wid == 3) {                // read key + |k|
      float kv = tanhf(sm.hr[lane]); sm.kr[lane] = kv;
      float s = wsum(kv * kv);
      if (lane == 0) sm.scal[14] = sqrtf(s);
    } else if (tid == 256) {              // write head scalars
      sm.scal[0] = softplusf_(sm.h[64]);
      sm.scal[1] = sigmoidf_(sm.h[65]);
      sm.scal[2] = 1.f + softplusf_(sm.h[69]);
      float a0 = sm.h[66], a1 = sm.h[67], a2 = sm.h[68];
      float mx = fmaxf(a0, fmaxf(a1, a2));
      float e0 = expf(a0 - mx), e1 = expf(a1 - mx), e2 = expf(a2 - mx);
      float d = 1.f / (e0 + e1 + e2);
      sm.scal[3] = e0 * d; sm.scal[4] = e1 * d; sm.scal[5] = e2 * d;
    } else if (tid == 320) {              // read head scalars
      sm.scal[8]  = softplusf_(sm.hr[64]);
      sm.scal[9]  = sigmoidf_(sm.hr[65]);
      sm.scal[10] = 1.f + softplusf_(sm.hr[69]);
      float a0 = sm.hr[66], a1 = sm.hr[67], a2 = sm.hr[68];
      float mx = fmaxf(a0, fmaxf(a1, a2));
      float e0 = expf(a0 - mx), e1 = expf(a1 - mx), e2 = expf(a2 - mx);
      float d = 1.f / (e0 + e1 + e2);
      sm.scal[11] = e0 * d; sm.scal[12] = e1 * d; sm.scal[13] = e2 * d;
    }
    __syncthreads();

    // ---- write head addressing
    float ww0, ww1;
    {
      float beta = sm.scal[0], g = sm.scal[1], gamma = sm.scal[2];
      float s0 = sm.scal[3], s1 = sm.scal[4], s2 = sm.scal[5], kn = sm.scal[6];
      float d0 = 0.f, d1 = 0.f;
      #pragma unroll
      for (int j = 0; j < kMV; ++j) {
        float kv = sm.k[j];
        d0 = fmaf(M0[j], kv, d0);
        d1 = fmaf(M1[j], kv, d1);
      }
      float sim0 = beta * d0 / (sqrtf(n2_0) * kn + kEPS);
      float sim1 = beta * d1 / (sqrtf(n2_1) * kn + kEPS);
      address2(sm, tid, lane, wid, sim0, sim1, g, s0, s1, s2, gamma, wp0, wp1, ww0, ww1);
    }

    // ---- memory update, fused with read-head dot + new row norm
    float dr0 = 0.f, dr1 = 0.f, nn0 = 0.f, nn1 = 0.f;
    #pragma unroll
    for (int j = 0; j < kMV; ++j) {
      float ev = sm.e[j], av = sm.a[j], kv = sm.kr[j];
      float m0 = fmaf(ww0, fmaf(-ev, M0[j], av), M0[j]);  // M*(1-w e) + w a
      float m1 = fmaf(ww1, fmaf(-ev, M1[j], av), M1[j]);
      M0[j] = m0; M1[j] = m1;
      dr0 = fmaf(m0, kv, dr0); nn0 = fmaf(m0, m0, nn0);
      dr1 = fmaf(m1, kv, dr1); nn1 = fmaf(m1, m1, nn1);
    }

    // ---- read head addressing (prev weights = write weights)
    float wr0, wr1;
    {
      float beta = sm.scal[8], g = sm.scal[9], gamma = sm.scal[10];
      float s0 = sm.scal[11], s1 = sm.scal[12], s2 = sm.scal[13], kn = sm.scal[14];
      float sim0 = beta * dr0 / (sqrtf(nn0) * kn + kEPS);
      float sim1 = beta * dr1 / (sqrtf(nn1) * kn + kEPS);
      address2(sm, tid, lane, wid, sim0, sim1, g, s0, s1, s2, gamma, ww0, ww1, wr0, wr1);
    }
    wp0 = wr0; wp1 = wr1; n2_0 = nn0; n2_1 = nn1;   // carry state

    // ---- read vector r[j] = sum_n w_r[n] M[n][j]  (chunked column reduce)
    #pragma unroll
    for (int cb = 0; cb < kMV; cb += 16) {
      #pragma unroll
      for (int u = 0; u < 16; ++u)
        sm.tmp[tid][u] = fmaf(wr0, M0[cb + u], wr1 * M1[cb + u]);
      __syncthreads();
      {
        int u2 = tid >> 5, i2 = tid & 31;   // 32 threads per column
        float s = 0.f;
        #pragma unroll
        for (int q = 0; q < 16; ++q) s += sm.tmp[i2 + 32 * q][u2];
        s += __shfl_xor(s, 16); s += __shfl_xor(s, 8);
        s += __shfl_xor(s, 4);  s += __shfl_xor(s, 2); s += __shfl_xor(s, 1);
        if (i2 == 0) sm.r[cb + u2] = s;
      }
      __syncthreads();
    }

    // ---- output: sigmoid([c, r] @ Wf + bf)  (64 outs, 320 in; 8 partials of 40)
    {
      const int j = tid & 63, p = tid >> 6;
      float s = 0.f;
      if constexpr (PACKED) {
        const TD* row = pWfT + j * (kC + kMV) + p * 40;  // contiguous 40 elems
        #pragma unroll
        for (int q = 0; q < 5; ++q) {
          float f[8]; ld8(row + 8 * q, f);
          #pragma unroll
          for (int u = 0; u < 8; ++u) {
            int idx = p * 40 + 8 * q + u;
            float v = (idx < kC) ? sm.c[idx] : sm.r[idx - kC];
            s = fmaf(v, f[u], s);
          }
        }
      } else {
        #pragma unroll
        for (int i = 0; i < 40; ++i) {
          int idx = p * 40 + i;
          float v = (idx < kC) ? sm.c[idx] : sm.r[idx - kC];
          s = fmaf(v, ldf(Wf, idx * kOUT + j), s);
        }
      }
      sm.part[p][j] = s;
    }
    __syncthreads();
    if (tid < kOUT) {
      float s = ldf(bf, tid);
      #pragma unroll
      for (int p = 0; p < 8; ++p) s += sm.part[p][tid];
      stf(out, (b * kT + t) * kOUT + tid, sigmoidf_(s));
    }
    __syncthreads();
  }
}

template <typename TD, int WANT, int PACKED>
static void launch_variant(void* const* d_in, void* d_out, const int* flag,
                           const void* pk, hipStream_t stream) {
  ntm_fused<TD, WANT, PACKED><<<dim3(kB), dim3(NT), 0, stream>>>(
      (const TD*)d_in[0], (const TD*)d_in[1], (const TD*)d_in[2],
      (const TD*)d_in[3], (const TD*)d_in[4], (const TD*)d_in[5],
      (const TD*)d_in[6], (const TD*)d_in[7], (const TD*)d_in[8],
      (const TD*)d_in[9], (const TD*)d_in[10], (const TD*)d_in[11],
      (const TD*)pk, (TD*)d_out, flag);
}

extern "C" void kernel_launch(void* const* d_in, const int* in_sizes, int n_in,
                              void* d_out, int out_size, void* d_ws, size_t ws_size,
                              hipStream_t stream) {
  (void)in_sizes; (void)n_in; (void)out_size;
  int* flag = (int*)d_ws;
  detect_dtype<<<dim3(1), dim3(64), 0, stream>>>(d_in[10], flag);
  if (ws_size >= kWsNeeded) {
    void* pk = (void*)((char*)d_ws + 256);
    repack_w<__hip_bfloat16, 1><<<dim3(256), dim3(256), 0, stream>>>(
        (const __hip_bfloat16*)d_in[1], (const __hip_bfloat16*)d_in[5],
        (const __hip_bfloat16*)d_in[3], (const __hip_bfloat16*)d_in[7],
        (__hip_bfloat16*)pk, flag);
    repack_w<float, 0><<<dim3(256), dim3(256), 0, stream>>>(
        (const float*)d_in[1], (const float*)d_in[5],
        (const float*)d_in[3], (const float*)d_in[7],
        (float*)pk, flag);
    launch_variant<__hip_bfloat16, 1, 1>(d_in, d_out, flag, pk, stream);
    launch_variant<float, 0, 1>(d_in, d_out, flag, pk, stream);
  } else {
    launch_variant<__hip_bfloat16, 1, 0>(d_in, d_out, flag, nullptr, stream);
    launch_variant<float, 0, 0>(d_in, d_out, flag, nullptr, stream);
  }
}

// Round 2
// 1537.797 us; speedup vs baseline: 1.8681x; 1.1367x over previous
//
#include <hip/hip_runtime.h>
#include <hip/hip_bf16.h>
#include <math.h>

// NTM forward, fully fused: one block per batch element, T=64 steps in-kernel.
// M[1024][64] fp32 lives in registers: 512 threads x 2 rows x 64 floats.
// Rev 3:
//  - __launch_bounds__(512, 1): the old (512,2) capped VGPRs at 128 == size of
//    M alone -> M spilled to scratch (10 MB WRITE_SIZE, ~200cy L2 round-trips
//    on the serial path). 1 block/CU is all we ever get (grid=64, 256 CUs), so
//    raise the cap to 256 and keep M in registers.
//  - barriers 23 -> 14 per step: h/hr intermediate folded into head-params
//    phase; address2 merges the wg-write barrier into the gsum barrier by
//    storing unnormalized E + WP and recomputing wg per neighbor (bit-identical
//    fmaf); read-vector uses an in-wave butterfly transpose-reduce (statically
//    indexed, no 34KB tmp buffer, 2 barriers instead of 8).
//  - x sequence (16KB) + all biases staged in LDS once; per-step staging phase
//    and per-step scalar global bias loads eliminated.
//  - float4 LDS reads for k/e/a/kr/c/x in hot loops (ds_read_b128).
//  - fast transcendentals (__expf/__logf/__fdividef): error ~1e-7 rel, far
//    below the bf16 quantization that dominates absmax.

constexpr int kB  = 64;
constexpr int kT  = 64;
constexpr int kIN = 64;
constexpr int kC  = 256;
constexpr int kN  = 1024;
constexpr int kMV = 64;
constexpr int kOUT = 64;
constexpr int kHW = 198;   // write head raw dim: MV+6+2*MV
constexpr int kHR = 70;    // read head raw dim: MV+6
constexpr int NT  = 512;   // threads per block (8 waves)
constexpr float kEPS = 1e-8f;

// packed (transposed) weight layout, offsets in elements
constexpr int kPWc = 0;                          // WcT [256][128]
constexpr int kPWw = kPWc + kC * 128;            // WwT [198][256] @ 32768
constexpr int kPWr = kPWw + kHW * kC;            // WrT [70][256]  @ 83456
constexpr int kPWf = kPWr + kHR * kC;            // WfT [64][320]  @ 101376
constexpr int kPTotal = kPWf + kOUT * (kC + kMV);  // 121856 elements
constexpr size_t kWsNeeded = 256 + (size_t)kPTotal * 4;  // fp32 worst case

__device__ __forceinline__ float ldf(const float* p, int i) { return p[i]; }
__device__ __forceinline__ float ldf(const __hip_bfloat16* p, int i) { return __bfloat162float(p[i]); }
__device__ __forceinline__ void stf(float* p, int i, float v) { p[i] = v; }
__device__ __forceinline__ void stf(__hip_bfloat16* p, int i, float v) { p[i] = __float2bfloat16(v); }

// 8 contiguous elements -> float[8]; 16B-aligned by construction.
__device__ __forceinline__ void ld8(const __hip_bfloat16* p, float* f) {
  uint4 u = *reinterpret_cast<const uint4*>(p);
  f[0] = __uint_as_float(u.x << 16); f[1] = __uint_as_float(u.x & 0xffff0000u);
  f[2] = __uint_as_float(u.y << 16); f[3] = __uint_as_float(u.y & 0xffff0000u);
  f[4] = __uint_as_float(u.z << 16); f[5] = __uint_as_float(u.z & 0xffff0000u);
  f[6] = __uint_as_float(u.w << 16); f[7] = __uint_as_float(u.w & 0xffff0000u);
}
__device__ __forceinline__ void ld8(const float* p, float* f) {
  float4 a = reinterpret_cast<const float4*>(p)[0];
  float4 b = reinterpret_cast<const float4*>(p)[1];
  f[0] = a.x; f[1] = a.y; f[2] = a.z; f[3] = a.w;
  f[4] = b.x; f[5] = b.y; f[6] = b.z; f[7] = b.w;
}

__device__ __forceinline__ float fexp(float v) { return __expf(v); }
__device__ __forceinline__ float sigmoidf_(float v) {
  return __fdividef(1.f, 1.f + __expf(-v));
}
__device__ __forceinline__ float softplusf_(float v) {
  return v > 20.f ? v : __logf(1.f + __expf(v));
}
__device__ __forceinline__ float ftanh(float v) {
  float a = fminf(fabsf(v), 15.f);          // exp(30) finite; tanh(15) == 1 in fp32
  float e = __expf(2.f * a);
  float t = 1.f - __fdividef(2.f, e + 1.f);
  return v < 0.f ? -t : t;
}

__device__ __forceinline__ float wsum(float v) {
  v += __shfl_xor(v, 32); v += __shfl_xor(v, 16); v += __shfl_xor(v, 8);
  v += __shfl_xor(v, 4);  v += __shfl_xor(v, 2);  v += __shfl_xor(v, 1);
  return v;
}
__device__ __forceinline__ float wmax(float v) {
  v = fmaxf(v, __shfl_xor(v, 32)); v = fmaxf(v, __shfl_xor(v, 16));
  v = fmaxf(v, __shfl_xor(v, 8));  v = fmaxf(v, __shfl_xor(v, 4));
  v = fmaxf(v, __shfl_xor(v, 2));  v = fmaxf(v, __shfl_xor(v, 1));
  return v;
}

struct Smem {
  // float4-read arrays first (16B alignment by element-offset multiples of 4)
  float xS[kT * kIN];       // whole input sequence for this batch element (16KB)
  float c[kC];              // controller activations
  float k[kMV], kr[kMV], e[kMV], a[kMV], r[kMV];
  float part[8][kC];        // GEMM partials / read-vector wave partials
  float E[kN];              // unnormalized content softmax numerators
  float WP[kN];             // previous weights (for shift conv)
  // scalar-read arrays
  float bcS[kC], bwS[kHW], brS[kHR], bfS[kOUT];   // biases (staged once)
  float red[3][8];          // cross-wave reduction slots
  float scal[16];           // 0..6 write head: beta,g,gamma,s0,s1,s2,|k| ; 8..14 read head
};
static_assert(sizeof(Smem) <= 160 * 1024, "LDS budget");

// address2 with 3 barriers (was 4): E/WP are written BEFORE the gsum barrier,
// and wg for the shifted neighbors is recomputed from E/WP with the identical
// fmaf expression -> bit-identical to materializing wg.
__device__ __forceinline__ void address2(Smem& sm, int tid, int lane, int wid,
                                         float sim0, float sim1,
                                         float g, float s0, float s1, float s2, float gamma,
                                         float wp0, float wp1,
                                         float& w0, float& w1) {
  float m = wmax(fmaxf(sim0, sim1));
  if (lane == 0) sm.red[0][wid] = m;
  __syncthreads();                                   // A
  float gmax = sm.red[0][0];
  #pragma unroll
  for (int i = 1; i < NT / 64; ++i) gmax = fmaxf(gmax, sm.red[0][i]);
  float e0 = fexp(sim0 - gmax), e1 = fexp(sim1 - gmax);
  sm.E[tid] = e0; sm.E[tid + NT] = e1;
  sm.WP[tid] = wp0; sm.WP[tid + NT] = wp1;
  float sv = wsum(e0 + e1);
  if (lane == 0) sm.red[1][wid] = sv;
  __syncthreads();                                   // B (covers gsum AND E/WP)
  float gsum = 0.f;
  #pragma unroll
  for (int i = 0; i < NT / 64; ++i) gsum += sm.red[1][i];
  float inv = __fdividef(1.f, gsum);
  float wg0 = fmaf(g, fmaf(e0, inv, -wp0), wp0);
  float wg1 = fmaf(g, fmaf(e1, inv, -wp1), wp1);
  // circular conv: s0*w[n+1] + s1*w[n] + s2*w[n-1]  (SHIFTS = -1,0,+1)
  int np = (tid + 1) & (kN - 1), nm = (tid + kN - 1) & (kN - 1);
  float ep = sm.E[np], pp = sm.WP[np], em = sm.E[nm], pm = sm.WP[nm];
  float wgp = fmaf(g, fmaf(ep, inv, -pp), pp);
  float wgm = fmaf(g, fmaf(em, inv, -pm), pm);
  float ws0 = s0 * wgp + s1 * wg0 + s2 * wgm;
  int npb = (tid + NT + 1) & (kN - 1), nmb = (tid + NT - 1) & (kN - 1);
  float epb = sm.E[npb], ppb = sm.WP[npb], emb = sm.E[nmb], pmb = sm.WP[nmb];
  float wgpb = fmaf(g, fmaf(epb, inv, -ppb), ppb);
  float wgmb = fmaf(g, fmaf(emb, inv, -pmb), pmb);
  float ws1 = s0 * wgpb + s1 * wg1 + s2 * wgmb;
  float p0 = fexp(gamma * __logf(ws0 + kEPS));
  float p1 = fexp(gamma * __logf(ws1 + kEPS));
  float pv = wsum(p0 + p1);
  if (lane == 0) sm.red[2][wid] = pv;
  __syncthreads();                                   // C
  float psum = 0.f;
  #pragma unroll
  for (int i = 0; i < NT / 64; ++i) psum += sm.red[2][i];
  float ipn = __fdividef(1.f, psum);
  w0 = p0 * ipn; w1 = p1 * ipn;
}

// flag: 1 if buffers are bf16, 0 if fp32.  w_bias is a softmax -> sums to 1.
__global__ void detect_dtype(const void* wb, int* flag) {
  const unsigned short* u = (const unsigned short*)wb;
  int lane = threadIdx.x;
  float s = 0.f;
  for (int i = lane; i < kN; i += 64)
    s += __uint_as_float(((unsigned int)u[i]) << 16);
  s = wsum(s);
  if (lane == 0 && blockIdx.x == 0)
    *flag = (s > 0.75f && s < 1.25f) ? 1 : 0;
}

// Transpose-repack the four weight matrices into workspace (coalesced writes).
template <typename TD, int WANT>
__global__ void repack_w(const TD* __restrict__ Wc, const TD* __restrict__ Ww,
                         const TD* __restrict__ Wr, const TD* __restrict__ Wf,
                         TD* __restrict__ pk, const int* __restrict__ flag) {
  if (*flag != WANT) return;
  for (int idx = blockIdx.x * blockDim.x + threadIdx.x; idx < kPTotal;
       idx += gridDim.x * blockDim.x) {
    TD v;
    if (idx < kPWw) {                       // WcT[j][i] = Wc[i][j], [128][256] src
      int r = idx, j = r >> 7, i = r & 127;
      v = Wc[i * kC + j];
    } else if (idx < kPWr) {                // WwT[j][i] = Ww[i][j], [256][198] src
      int r = idx - kPWw, j = r >> 8, i = r & 255;
      v = Ww[i * kHW + j];
    } else if (idx < kPWf) {                // WrT[j][i] = Wr[i][j], [256][70] src
      int r = idx - kPWr, j = r >> 8, i = r & 255;
      v = Wr[i * kHR + j];
    } else {                                // WfT[j][i] = Wf[i][j], [320][64] src
      int r = idx - kPWf, j = r / 320, i = r % 320;
      v = Wf[i * kOUT + j];
    }
    pk[idx] = v;
  }
}

template <typename TD, int WANT, int PACKED>
__global__ __launch_bounds__(NT, 1) void ntm_fused(
    const TD* __restrict__ x,
    const TD* __restrict__ Wc, const TD* __restrict__ bc,
    const TD* __restrict__ Wr, const TD* __restrict__ br,
    const TD* __restrict__ Ww, const TD* __restrict__ bw,
    const TD* __restrict__ Wf, const TD* __restrict__ bf,
    const TD* __restrict__ r_bias, const TD* __restrict__ w_bias,
    const TD* __restrict__ M_bias,
    const TD* __restrict__ pk,
    TD* __restrict__ out, const int* __restrict__ flag) {
  if (*flag != WANT) return;
  __shared__ Smem sm;
  const int tid  = threadIdx.x;
  const int b    = blockIdx.x;
  const int lane = tid & 63;
  const int wid  = tid >> 6;

  const TD* pWcT = pk + kPWc;
  const TD* pWwT = pk + kPWw;
  const TD* pWrT = pk + kPWr;
  const TD* pWfT = pk + kPWf;

  // ---- one-time staging: whole x sequence (vectorized), biases, r_bias
  {
    float f[8]; ld8(x + (size_t)b * kT * kIN + tid * 8, f);
    #pragma unroll
    for (int u = 0; u < 8; ++u) sm.xS[tid * 8 + u] = f[u];
  }
  if (tid < kC)  sm.bcS[tid] = ldf(bc, tid);
  if (tid < kHW) sm.bwS[tid] = ldf(bw, tid);
  if (tid < kHR) sm.brS[tid] = ldf(br, tid);
  if (tid < kOUT) sm.bfS[tid] = ldf(bf, tid);
  if (tid < kMV) sm.r[tid] = ldf(r_bias, tid);

  // ---- init state: M rows (registers), row norms, prev weights
  float M0[kMV], M1[kMV];
  float n2_0 = 0.f, n2_1 = 0.f;
  #pragma unroll
  for (int jb = 0; jb < kMV; jb += 8) {
    float f0[8], f1[8];
    ld8(M_bias + tid * kMV + jb, f0);
    ld8(M_bias + (tid + NT) * kMV + jb, f1);
    #pragma unroll
    for (int u = 0; u < 8; ++u) {
      M0[jb + u] = f0[u]; M1[jb + u] = f1[u];
      n2_0 = fmaf(f0[u], f0[u], n2_0);
      n2_1 = fmaf(f1[u], f1[u], n2_1);
    }
  }
  float wp0 = ldf(w_bias, tid);
  float wp1 = ldf(w_bias, tid + NT);
  __syncthreads();

  #pragma unroll 1
  for (int t = 0; t < kT; ++t) {
    // ---- controller: c = tanh([x_t, r] @ Wc + bc)  (x from LDS, r from LDS)
    {
      const int j = tid & 255, p = tid >> 8;
      const float* inp = (p == 0) ? &sm.xS[t * kIN] : sm.r;  // wave-uniform
      float s = 0.f;
      if constexpr (PACKED) {
        const TD* row = pWcT + j * 128 + p * 64;   // contiguous 64 elems
        #pragma unroll
        for (int q = 0; q < 8; ++q) {
          float f[8]; ld8(row + 8 * q, f);
          float4 xa = *(const float4*)&inp[8 * q];
          float4 xb = *(const float4*)&inp[8 * q + 4];
          s = fmaf(xa.x, f[0], s); s = fmaf(xa.y, f[1], s);
          s = fmaf(xa.z, f[2], s); s = fmaf(xa.w, f[3], s);
          s = fmaf(xb.x, f[4], s); s = fmaf(xb.y, f[5], s);
          s = fmaf(xb.z, f[6], s); s = fmaf(xb.w, f[7], s);
        }
      } else {
        #pragma unroll 8
        for (int i = 0; i < 64; ++i)
          s = fmaf(inp[i], ldf(Wc, (p * 64 + i) * kC + j), s);
      }
      sm.part[p][j] = s;
    }
    __syncthreads();                                               // 1
    if (tid < kC) sm.c[tid] = ftanh(sm.part[0][tid] + sm.part[1][tid] + sm.bcS[tid]);
    __syncthreads();                                               // 2

    // ---- head GEMVs: hw = c @ Ww + bw (198), hr = c @ Wr + br (70)
    {
      const int j = tid & 255, p = tid >> 8;
      if (j < kHW) {
        float s = 0.f;
        if constexpr (PACKED) {
          const TD* row = pWwT + j * kC + p * 128;
          #pragma unroll
          for (int q = 0; q < 16; ++q) {
            float f[8]; ld8(row + 8 * q, f);
            float4 ca = *(const float4*)&sm.c[p * 128 + 8 * q];
            float4 cb = *(const float4*)&sm.c[p * 128 + 8 * q + 4];
            s = fmaf(ca.x, f[0], s); s = fmaf(ca.y, f[1], s);
            s = fmaf(ca.z, f[2], s); s = fmaf(ca.w, f[3], s);
            s = fmaf(cb.x, f[4], s); s = fmaf(cb.y, f[5], s);
            s = fmaf(cb.z, f[6], s); s = fmaf(cb.w, f[7], s);
          }
        } else {
          #pragma unroll 8
          for (int i = 0; i < 128; ++i)
            s = fmaf(sm.c[p * 128 + i], ldf(Ww, (p * 128 + i) * kHW + j), s);
        }
        sm.part[p][j] = s;
      }
      if (j < kHR) {
        float s = 0.f;
        if constexpr (PACKED) {
          const TD* row = pWrT + j * kC + p * 128;
          #pragma unroll
          for (int q = 0; q < 16; ++q) {
            float f[8]; ld8(row + 8 * q, f);
            float4 ca = *(const float4*)&sm.c[p * 128 + 8 * q];
            float4 cb = *(const float4*)&sm.c[p * 128 + 8 * q + 4];
            s = fmaf(ca.x, f[0], s); s = fmaf(ca.y, f[1], s);
            s = fmaf(ca.z, f[2], s); s = fmaf(ca.w, f[3], s);
            s = fmaf(cb.x, f[4], s); s = fmaf(cb.y, f[5], s);
            s = fmaf(cb.z, f[6], s); s = fmaf(cb.w, f[7], s);
          }
        } else {
          #pragma unroll 8
          for (int i = 0; i < 128; ++i)
            s = fmaf(sm.c[p * 128 + i], ldf(Wr, (p * 128 + i) * kHR + j), s);
        }
        sm.part[2 + p][j] = s;
      }
    }
    __syncthreads();                                               // 3

    // ---- head params, fused with partial-sum + bias (h/hr never materialized)
    if (wid == 0) {                       // write key + |k|
      float kv = ftanh(sm.part[0][lane] + sm.part[1][lane] + sm.bwS[lane]);
      sm.k[lane] = kv;
      float s = wsum(kv * kv);
      if (lane == 0) sm.scal[6] = sqrtf(s);
    } else if (wid == 1) {                // erase
      int j = 70 + lane;
      sm.e[lane] = sigmoidf_(sm.part[0][j] + sm.part[1][j] + sm.bwS[j]);
    } else if (wid == 2) {                // add
      int j = 134 + lane;
      sm.a[lane] = ftanh(sm.part[0][j] + sm.part[1][j] + sm.bwS[j]);
    } else if (wid == 3) {                // read key + |k|
      float kv = ftanh(sm.part[2][lane] + sm.part[3][lane] + sm.brS[lane]);
      sm.kr[lane] = kv;
      float s = wsum(kv * kv);
      if (lane == 0) sm.scal[14] = sqrtf(s);
    } else if (tid == 256) {              // write head scalars
      float h64 = sm.part[0][64] + sm.part[1][64] + sm.bwS[64];
      float h65 = sm.part[0][65] + sm.part[1][65] + sm.bwS[65];
      float a0  = sm.part[0][66] + sm.part[1][66] + sm.bwS[66];
      float a1  = sm.part[0][67] + sm.part[1][67] + sm.bwS[67];
      float a2  = sm.part[0][68] + sm.part[1][68] + sm.bwS[68];
      float h69 = sm.part[0][69] + sm.part[1][69] + sm.bwS[69];
      sm.scal[0] = softplusf_(h64);
      sm.scal[1] = sigmoidf_(h65);
      sm.scal[2] = 1.f + softplusf_(h69);
      float mx = fmaxf(a0, fmaxf(a1, a2));
      float e0 = fexp(a0 - mx), e1 = fexp(a1 - mx), e2 = fexp(a2 - mx);
      float d = __fdividef(1.f, e0 + e1 + e2);
      sm.scal[3] = e0 * d; sm.scal[4] = e1 * d; sm.scal[5] = e2 * d;
    } else if (tid == 320) {              // read head scalars
      float h64 = sm.part[2][64] + sm.part[3][64] + sm.brS[64];
      float h65 = sm.part[2][65] + sm.part[3][65] + sm.brS[65];
      float a0  = sm.part[2][66] + sm.part[3][66] + sm.brS[66];
      float a1  = sm.part[2][67] + sm.part[3][67] + sm.brS[67];
      float a2  = sm.part[2][68] + sm.part[3][68] + sm.brS[68];
      float h69 = sm.part[2][69] + sm.part[3][69] + sm.brS[69];
      sm.scal[8]  = softplusf_(h64);
      sm.scal[9]  = sigmoidf_(h65);
      sm.scal[10] = 1.f + softplusf_(h69);
      float mx = fmaxf(a0, fmaxf(a1, a2));
      float e0 = fexp(a0 - mx), e1 = fexp(a1 - mx), e2 = fexp(a2 - mx);
      float d = __fdividef(1.f, e0 + e1 + e2);
      sm.scal[11] = e0 * d; sm.scal[12] = e1 * d; sm.scal[13] = e2 * d;
    }
    __syncthreads();                                               // 4

    // ---- write head addressing
    float ww0, ww1;
    {
      float beta = sm.scal[0], g = sm.scal[1], gamma = sm.scal[2];
      float s0 = sm.scal[3], s1 = sm.scal[4], s2 = sm.scal[5], kn = sm.scal[6];
      float d0 = 0.f, d1 = 0.f;
      #pragma unroll
      for (int jb = 0; jb < kMV; jb += 4) {
        float4 kv = *(const float4*)&sm.k[jb];
        d0 = fmaf(M0[jb], kv.x, d0);     d1 = fmaf(M1[jb], kv.x, d1);
        d0 = fmaf(M0[jb + 1], kv.y, d0); d1 = fmaf(M1[jb + 1], kv.y, d1);
        d0 = fmaf(M0[jb + 2], kv.z, d0); d1 = fmaf(M1[jb + 2], kv.z, d1);
        d0 = fmaf(M0[jb + 3], kv.w, d0); d1 = fmaf(M1[jb + 3], kv.w, d1);
      }
      float sim0 = beta * d0 / (sqrtf(n2_0) * kn + kEPS);
      float sim1 = beta * d1 / (sqrtf(n2_1) * kn + kEPS);
      address2(sm, tid, lane, wid, sim0, sim1, g, s0, s1, s2, gamma, wp0, wp1, ww0, ww1);
    }                                                              // 5,6,7

    // ---- memory update, fused with read-head dot + new row norm (float4 LDS)
    float dr0 = 0.f, dr1 = 0.f, nn0 = 0.f, nn1 = 0.f;
    #pragma unroll
    for (int jb = 0; jb < kMV; jb += 4) {
      float4 ev = *(const float4*)&sm.e[jb];
      float4 av = *(const float4*)&sm.a[jb];
      float4 kv = *(const float4*)&sm.kr[jb];
      {
        float m0 = fmaf(ww0, fmaf(-ev.x, M0[jb], av.x), M0[jb]);
        float m1 = fmaf(ww1, fmaf(-ev.x, M1[jb], av.x), M1[jb]);
        M0[jb] = m0; M1[jb] = m1;
        dr0 = fmaf(m0, kv.x, dr0); nn0 = fmaf(m0, m0, nn0);
        dr1 = fmaf(m1, kv.x, dr1); nn1 = fmaf(m1, m1, nn1);
      }
      {
        float m0 = fmaf(ww0, fmaf(-ev.y, M0[jb + 1], av.y), M0[jb + 1]);
        float m1 = fmaf(ww1, fmaf(-ev.y, M1[jb + 1], av.y), M1[jb + 1]);
        M0[jb + 1] = m0; M1[jb + 1] = m1;
        dr0 = fmaf(m0, kv.y, dr0); nn0 = fmaf(m0, m0, nn0);
        dr1 = fmaf(m1, kv.y, dr1); nn1 = fmaf(m1, m1, nn1);
      }
      {
        float m0 = fmaf(ww0, fmaf(-ev.z, M0[jb + 2], av.z), M0[jb + 2]);
        float m1 = fmaf(ww1, fmaf(-ev.z, M1[jb + 2], av.z), M1[jb + 2]);
        M0[jb + 2] = m0; M1[jb + 2] = m1;
        dr0 = fmaf(m0, kv.z, dr0); nn0 = fmaf(m0, m0, nn0);
        dr1 = fmaf(m1, kv.z, dr1); nn1 = fmaf(m1, m1, nn1);
      }
      {
        float m0 = fmaf(ww0, fmaf(-ev.w, M0[jb + 3], av.w), M0[jb + 3]);
        float m1 = fmaf(ww1, fmaf(-ev.w, M1[jb + 3], av.w), M1[jb + 3]);
        M0[jb + 3] = m0; M1[jb + 3] = m1;
        dr0 = fmaf(m0, kv.w, dr0); nn0 = fmaf(m0, m0, nn0);
        dr1 = fmaf(m1, kv.w, dr1); nn1 = fmaf(m1, m1, nn1);
      }
    }

    // ---- read head addressing (prev weights = write weights)
    float wr0, wr1;
    {
      float beta = sm.scal[8], g = sm.scal[9], gamma = sm.scal[10];
      float s0 = sm.scal[11], s1 = sm.scal[12], s2 = sm.scal[13], kn = sm.scal[14];
      float sim0 = beta * dr0 / (sqrtf(nn0) * kn + kEPS);
      float sim1 = beta * dr1 / (sqrtf(nn1) * kn + kEPS);
      address2(sm, tid, lane, wid, sim0, sim1, g, s0, s1, s2, gamma, ww0, ww1, wr0, wr1);
    }                                                              // 8,9,10
    wp0 = wr0; wp1 = wr1; n2_0 = nn0; n2_1 = nn1;   // carry state

    // ---- read vector r[j] = sum_n w_r[n] M[n][j]
    // in-wave butterfly transpose-reduce: after 6 stages lane l holds column
    // l's sum over its wave. All array indices compile-time (rule #20).
    {
      float cur[32];
      const int b0 = lane & 1;
      #pragma unroll
      for (int q = 0; q < 32; ++q) {
        float v0 = fmaf(wr0, M0[2 * q],     wr1 * M1[2 * q]);
        float v1 = fmaf(wr0, M0[2 * q + 1], wr1 * M1[2 * q + 1]);
        float keep = b0 ? v1 : v0;
        float send = b0 ? v0 : v1;
        cur[q] = keep + __shfl_xor(send, 1);
      }
      #pragma unroll
      for (int st = 1; st < 6; ++st) {
        const int d = 1 << st;
        const int bb = (lane >> st) & 1;
        #pragma unroll
        for (int q = 0; q < (32 >> st); ++q) {
          float x0 = cur[2 * q], x1 = cur[2 * q + 1];
          float keep = bb ? x1 : x0;
          float send = bb ? x0 : x1;
          cur[q] = keep + __shfl_xor(send, d);
        }
      }
      sm.part[wid][lane] = cur[0];
    }
    __syncthreads();                                               // 11
    if (tid < kMV) {
      float s = sm.part[0][tid];
      #pragma unroll
      for (int w = 1; w < 8; ++w) s += sm.part[w][tid];
      sm.r[tid] = s;
    }
    __syncthreads();                                               // 12

    // ---- output: sigmoid([c, r] @ Wf + bf)  (64 outs, 320 in; 8 partials of 40)
    {
      const int j = tid & 63, p = tid >> 6;
      float s = 0.f;
      if constexpr (PACKED) {
        const TD* row = pWfT + j * (kC + kMV) + p * 40;
        #pragma unroll
        for (int q = 0; q < 5; ++q) {
          int idx0 = p * 40 + 8 * q;     // multiple of 8; c/r boundary at 256 is chunk-aligned
          const float* src = (idx0 < kC) ? &sm.c[idx0] : &sm.r[idx0 - kC];
          float f[8]; ld8(row + 8 * q, f);
          float4 va = *(const float4*)src;
          float4 vb = *(const float4*)(src + 4);
          s = fmaf(va.x, f[0], s); s = fmaf(va.y, f[1], s);
          s = fmaf(va.z, f[2], s); s = fmaf(va.w, f[3], s);
          s = fmaf(vb.x, f[4], s); s = fmaf(vb.y, f[5], s);
          s = fmaf(vb.z, f[6], s); s = fmaf(vb.w, f[7], s);
        }
      } else {
        #pragma unroll
        for (int i = 0; i < 40; ++i) {
          int idx = p * 40 + i;
          float v = (idx < kC) ? sm.c[idx] : sm.r[idx - kC];
          s = fmaf(v, ldf(Wf, idx * kOUT + j), s);
        }
      }
      sm.part[p][j] = s;
    }
    __syncthreads();                                               // 13
    if (tid < kOUT) {
      float s = sm.bfS[tid];
      #pragma unroll
      for (int p = 0; p < 8; ++p) s += sm.part[p][tid];
      stf(out, (b * kT + t) * kOUT + tid, sigmoidf_(s));
    }
    __syncthreads();                                               // 14
  }
}

template <typename TD, int WANT, int PACKED>
static void launch_variant(void* const* d_in, void* d_out, const int* flag,
                           const void* pk, hipStream_t stream) {
  ntm_fused<TD, WANT, PACKED><<<dim3(kB), dim3(NT), 0, stream>>>(
      (const TD*)d_in[0], (const TD*)d_in[1], (const TD*)d_in[2],
      (const TD*)d_in[3], (const TD*)d_in[4], (const TD*)d_in[5],
      (const TD*)d_in[6], (const TD*)d_in[7], (const TD*)d_in[8],
      (const TD*)d_in[9], (const TD*)d_in[10], (const TD*)d_in[11],
      (const TD*)pk, (TD*)d_out, flag);
}

extern "C" void kernel_launch(void* const* d_in, const int* in_sizes, int n_in,
                              void* d_out, int out_size, void* d_ws, size_t ws_size,
                              hipStream_t stream) {
  (void)in_sizes; (void)n_in; (void)out_size;
  int* flag = (int*)d_ws;
  detect_dtype<<<dim3(1), dim3(64), 0, stream>>>(d_in[10], flag);
  if (ws_size >= kWsNeeded) {
    void* pk = (void*)((char*)d_ws + 256);
    repack_w<__hip_bfloat16, 1><<<dim3(256), dim3(256), 0, stream>>>(
        (const __hip_bfloat16*)d_in[1], (const __hip_bfloat16*)d_in[5],
        (const __hip_bfloat16*)d_in[3], (const __hip_bfloat16*)d_in[7],
        (__hip_bfloat16*)pk, flag);
    repack_w<float, 0><<<dim3(256), dim3(256), 0, stream>>>(
        (const float*)d_in[1], (const float*)d_in[5],
        (const float*)d_in[3], (const float*)d_in[7],
        (float*)pk, flag);
    launch_variant<__hip_bfloat16, 1, 1>(d_in, d_out, flag, pk, stream);
    launch_variant<float, 0, 1>(d_in, d_out, flag, pk, stream);
  } else {
    launch_variant<__hip_bfloat16, 1, 0>(d_in, d_out, flag, nullptr, stream);
    launch_variant<float, 0, 0>(d_in, d_out, flag, nullptr, stream);
  }
}